// Round 1
// baseline (1215.662 us; speedup 1.0000x reference)
//
#include <hip/hip_runtime.h>
#include <math.h>

// ---------------------------------------------------------------------------
// GCN 2-layer: h1 = relu(gcnconv(x,W1,b1)); out = log_softmax(gcnconv(h1,W2,b2))
// gcnconv: h = x@W; agg[c] += h[r]*dinv[r]*dinv[c] over edges; + h*dinv^2 + b
// N=100000, E=1600000, F: 512 -> 64 -> 40
// ---------------------------------------------------------------------------

#define FIN 512
#define FHID 64
#define FOUT 40

// ---------------- degree ----------------
__global__ void deg_kernel(const int* __restrict__ col, float* __restrict__ deg, int E) {
    int e = blockIdx.x * 256 + threadIdx.x;
    if (e < E) atomicAdd(&deg[col[e]], 1.0f);
}

__global__ void dinv_kernel(float* __restrict__ deg, int n) {
    int i = blockIdx.x * 256 + threadIdx.x;
    if (i < n) deg[i] = rsqrtf(deg[i] + 1.0f);
}

// ---------------- GEMM1: h1[N,64] = x[N,512] @ W1[512,64] ----------------
// Block: 256 threads = 16x16; BM=64 nodes, BN=64 cols, BK=64; 4x4 per-thread tile.
__global__ __launch_bounds__(256) void gemm1_kernel(
    const float* __restrict__ x, const float* __restrict__ W1,
    float* __restrict__ h1, int n) {
    __shared__ __align__(16) float lw[64 * 64];   // [k][col]
    __shared__ __align__(16) float lx[64 * 68];   // [k][node], padded +4

    int tid = threadIdx.x;
    int tx = tid & 15;        // col tile
    int ty = tid >> 4;        // node tile
    int node0 = blockIdx.x * 64;
    int kl = tid & 63;

    float acc[4][4];
#pragma unroll
    for (int i = 0; i < 4; ++i)
#pragma unroll
        for (int j = 0; j < 4; ++j) acc[i][j] = 0.f;

    for (int kc = 0; kc < FIN; kc += 64) {
        __syncthreads();
        // stage W chunk: 4096 elems
#pragma unroll
        for (int r = 0; r < 16; ++r) {
            int idx = tid + r * 256;            // idx = k*64 + col
            lw[idx] = W1[(kc + (idx >> 6)) * 64 + (idx & 63)];
        }
        // stage x chunk transposed: lx[k][m]
#pragma unroll
        for (int r = 0; r < 16; ++r) {
            int m = (tid >> 6) + r * 4;
            int node = node0 + m;
            float v = (node < n) ? x[node * FIN + kc + kl] : 0.f;
            lx[kl * 68 + m] = v;
        }
        __syncthreads();

#pragma unroll 8
        for (int k = 0; k < 64; ++k) {
            const float4 av = *reinterpret_cast<const float4*>(&lx[k * 68 + ty * 4]);
            const float4 bv = *reinterpret_cast<const float4*>(&lw[k * 64 + tx * 4]);
            float a[4] = {av.x, av.y, av.z, av.w};
            float b[4] = {bv.x, bv.y, bv.z, bv.w};
#pragma unroll
            for (int i = 0; i < 4; ++i)
#pragma unroll
                for (int j = 0; j < 4; ++j)
                    acc[i][j] = fmaf(a[i], b[j], acc[i][j]);
        }
    }

#pragma unroll
    for (int i = 0; i < 4; ++i) {
        int node = node0 + ty * 4 + i;
        if (node < n) {
            float4 o = make_float4(acc[i][0], acc[i][1], acc[i][2], acc[i][3]);
            *reinterpret_cast<float4*>(&h1[node * 64 + tx * 4]) = o;
        }
    }
}

// ---------------- scatter layer 1: 64 features ----------------
__global__ void scatter1_kernel(const int* __restrict__ row, const int* __restrict__ col,
                                const float* __restrict__ dinv, const float* __restrict__ h1,
                                float* __restrict__ agg, int E) {
    int gid = blockIdx.x * 256 + threadIdx.x;   // E*64 = 102.4M < 2^31
    int e = gid >> 6;
    int j = gid & 63;
    if (e < E) {
        int r = row[e], c = col[e];
        float nrm = dinv[r] * dinv[c];
        atomicAdd(&agg[c * 64 + j], h1[r * 64 + j] * nrm);
    }
}

// ---------------- combine1 + bias + relu (in place into agg -> h) ----------------
__global__ void combine1_kernel(float* __restrict__ agg, const float* __restrict__ h1,
                                const float* __restrict__ dinv, const float* __restrict__ b1,
                                int n) {
    int gid = blockIdx.x * 256 + threadIdx.x;
    int i = gid >> 6, j = gid & 63;
    if (i < n) {
        float di = dinv[i];
        float v = agg[gid] + h1[gid] * di * di + b1[j];
        agg[gid] = fmaxf(v, 0.f);
    }
}

// ---------------- GEMM2: h2[N,40] = h[N,64] @ W2[64,40] ----------------
__global__ __launch_bounds__(256) void gemm2_kernel(const float* __restrict__ h,
                                                    const float* __restrict__ W2,
                                                    float* __restrict__ h2, int n) {
    __shared__ float lw[64 * 40];
    int tid = threadIdx.x;
#pragma unroll
    for (int r = 0; r < 10; ++r) lw[tid + r * 256] = W2[tid + r * 256];
    __syncthreads();
    int gid = blockIdx.x * 256 + tid;
    if (gid < n * FOUT) {
        int i = gid / FOUT;
        int j = gid - i * FOUT;
        const float* hrow = h + i * 64;
        float acc = 0.f;
#pragma unroll
        for (int k = 0; k < 64; ++k) acc = fmaf(hrow[k], lw[k * FOUT + j], acc);
        h2[gid] = acc;
    }
}

// ---------------- scatter layer 2: 40 features ----------------
__global__ void scatter2_kernel(const int* __restrict__ row, const int* __restrict__ col,
                                const float* __restrict__ dinv, const float* __restrict__ h2,
                                float* __restrict__ agg2, int E) {
    int gid = blockIdx.x * 256 + threadIdx.x;   // E*40 = 64M < 2^31
    if (gid < E * FOUT) {
        int e = gid / FOUT;
        int j = gid - e * FOUT;
        int r = row[e], c = col[e];
        float nrm = dinv[r] * dinv[c];
        atomicAdd(&agg2[c * FOUT + j], h2[r * FOUT + j] * nrm);
    }
}

// ---------------- final: self-loop + bias + log_softmax ----------------
__global__ __launch_bounds__(256) void final_kernel(const float* __restrict__ agg2,
                                                    const float* __restrict__ h2,
                                                    const float* __restrict__ dinv,
                                                    const float* __restrict__ b2,
                                                    float* __restrict__ out, int n) {
    int tid = threadIdx.x;
    int lane = tid & 63;
    int node = blockIdx.x * 4 + (tid >> 6);
    if (node >= n) return;
    float di = dinv[node];
    float dd = di * di;
    float raw = 0.f;
    float v = -INFINITY;
    if (lane < FOUT) {
        int idx = node * FOUT + lane;
        raw = agg2[idx] + h2[idx] * dd + b2[lane];
        v = raw;
    }
    float m = v;
#pragma unroll
    for (int off = 32; off > 0; off >>= 1) m = fmaxf(m, __shfl_down(m, off));
    m = __shfl(m, 0);
    float ex = (lane < FOUT) ? expf(raw - m) : 0.f;
    float s = ex;
#pragma unroll
    for (int off = 32; off > 0; off >>= 1) s += __shfl_down(s, off);
    s = __shfl(s, 0);
    float ls = logf(s);
    if (lane < FOUT) out[node * FOUT + lane] = raw - m - ls;
}

// ---------------------------------------------------------------------------
extern "C" void kernel_launch(void* const* d_in, const int* in_sizes, int n_in,
                              void* d_out, int out_size, void* d_ws, size_t ws_size,
                              hipStream_t stream) {
    const float* x  = (const float*)d_in[0];
    const int*   ei = (const int*)d_in[1];
    const float* W1 = (const float*)d_in[2];
    const float* b1 = (const float*)d_in[3];
    const float* W2 = (const float*)d_in[4];
    const float* b2 = (const float*)d_in[5];
    float* out = (float*)d_out;

    int n = in_sizes[0] / FIN;        // 100000
    int E = in_sizes[1] / 2;          // 1600000
    const int* row = ei;
    const int* col = ei + E;

    // workspace layout (floats):
    //   dinv  [n]               @ 0
    //   h1    [n*64]            @ A        (later aliased by agg2 [n*40])
    //   agg1  [n*64]            @ A + n*64 (becomes h after combine1)
    //   h2    [n*40]            @ A + 2*n*64
    float* ws   = (float*)d_ws;
    size_t A    = 102400;  // aligned past dinv
    float* dinv = ws;
    float* h1   = ws + A;
    float* agg1 = h1 + (size_t)n * 64;
    float* h2   = agg1 + (size_t)n * 64;
    float* agg2 = h1;  // alias: h1 dead after combine1

    // ---- degree ----
    hipMemsetAsync(dinv, 0, (size_t)n * 4, stream);
    hipMemsetAsync(agg1, 0, (size_t)n * 64 * 4, stream);
    deg_kernel<<<(E + 255) / 256, 256, 0, stream>>>(col, dinv, E);
    dinv_kernel<<<(n + 255) / 256, 256, 0, stream>>>(dinv, n);

    // ---- layer 1 ----
    gemm1_kernel<<<(n + 63) / 64, 256, 0, stream>>>(x, W1, h1, n);
    scatter1_kernel<<<(E * 64) / 256, 256, 0, stream>>>(row, col, dinv, h1, agg1, E);
    combine1_kernel<<<(n * 64) / 256, 256, 0, stream>>>(agg1, h1, dinv, b1, n);
    // agg1 now holds h (post-relu); h1 is dead

    // ---- layer 2 ----
    hipMemsetAsync(agg2, 0, (size_t)n * FOUT * 4, stream);
    gemm2_kernel<<<(n * FOUT + 255) / 256, 256, 0, stream>>>(agg1, W2, h2, n);
    scatter2_kernel<<<((size_t)E * FOUT + 255) / 256, 256, 0, stream>>>(row, col, dinv, h2, agg2, E);
    final_kernel<<<(n + 3) / 4, 256, 0, stream>>>(agg2, h2, dinv, b2, out, n);
}

// Round 2
// 841.539 us; speedup vs baseline: 1.4446x; 1.4446x over previous
//
#include <hip/hip_runtime.h>
#include <math.h>

// ---------------------------------------------------------------------------
// GCN 2-layer: h1 = relu(gcnconv(x,W1,b1)); out = log_softmax(gcnconv(h1,W2,b2))
// Strategy: transform-first (F_out < F_in both layers), then CSR-by-destination
// gather aggregation (no atomics in the hot path).
// N=100000, E=1600000, F: 512 -> 64 -> 40
// ---------------------------------------------------------------------------

#define FIN 512
#define FHID 64
#define FOUT 40

// ---------------- histogram of in-degree (int) ----------------
__global__ void hist_kernel(const int* __restrict__ col, int* __restrict__ deg, int E) {
    int e = blockIdx.x * 256 + threadIdx.x;
    if (e < E) atomicAdd(&deg[col[e]], 1);
}

__global__ void dinv_kernel(const int* __restrict__ deg, float* __restrict__ dinv, int n) {
    int i = blockIdx.x * 256 + threadIdx.x;
    if (i < n) dinv[i] = rsqrtf((float)deg[i] + 1.0f);
}

// ---------------- scan: offsets = exclusive_prefix(deg) ----------------
__global__ void scan1_kernel(const int* __restrict__ deg, int* __restrict__ offs,
                             int* __restrict__ bsums, int n) {
    __shared__ int tmp[256];
    int tid = threadIdx.x;
    int i = blockIdx.x * 256 + tid;
    int v = (i < n) ? deg[i] : 0;
    tmp[tid] = v;
    __syncthreads();
    for (int off = 1; off < 256; off <<= 1) {
        int t = (tid >= off) ? tmp[tid - off] : 0;
        __syncthreads();
        tmp[tid] += t;
        __syncthreads();
    }
    if (i < n) offs[i] = tmp[tid] - v;          // exclusive within block
    if (tid == 255) bsums[blockIdx.x] = tmp[255];
}

__global__ void scan2_kernel(int* __restrict__ bsums, int nb) {
    __shared__ int tmp[512];
    int tid = threadIdx.x;
    int v = (tid < nb) ? bsums[tid] : 0;
    tmp[tid] = v;
    __syncthreads();
    for (int off = 1; off < 512; off <<= 1) {
        int t = (tid >= off) ? tmp[tid - off] : 0;
        __syncthreads();
        tmp[tid] += t;
        __syncthreads();
    }
    if (tid < nb) bsums[tid] = tmp[tid] - v;    // exclusive block bases
}

__global__ void scan3_kernel(int* __restrict__ offs, const int* __restrict__ bsums,
                             int* __restrict__ cursor, int n) {
    int i = blockIdx.x * 256 + threadIdx.x;
    if (i < n) {
        int o = offs[i] + bsums[blockIdx.x];
        offs[i] = o;
        cursor[i] = o;
    }
}

// ---------------- build sorted edge list (by destination) ----------------
__global__ void build_kernel(const int* __restrict__ row, const int* __restrict__ col,
                             const float* __restrict__ dinv, int* __restrict__ cursor,
                             int* __restrict__ sRow, float* __restrict__ sNorm, int E) {
    int e = blockIdx.x * 256 + threadIdx.x;
    if (e < E) {
        int r = row[e], c = col[e];
        float nm = dinv[r] * dinv[c];
        int pos = atomicAdd(&cursor[c], 1);
        sRow[pos] = r;
        sNorm[pos] = nm;
    }
}

// ---------------- GEMM1: h1[N,64] = x[N,512] @ W1[512,64] ----------------
__global__ __launch_bounds__(256) void gemm1_kernel(
    const float* __restrict__ x, const float* __restrict__ W1,
    float* __restrict__ h1, int n) {
    __shared__ __align__(16) float lw[64 * 64];   // [k][col]
    __shared__ __align__(16) float lx[64 * 68];   // [k][node], padded +4

    int tid = threadIdx.x;
    int tx = tid & 15;        // col tile
    int ty = tid >> 4;        // node tile
    int node0 = blockIdx.x * 64;
    int kl = tid & 63;

    float acc[4][4];
#pragma unroll
    for (int i = 0; i < 4; ++i)
#pragma unroll
        for (int j = 0; j < 4; ++j) acc[i][j] = 0.f;

    for (int kc = 0; kc < FIN; kc += 64) {
        __syncthreads();
#pragma unroll
        for (int r = 0; r < 16; ++r) {
            int idx = tid + r * 256;            // idx = k*64 + col
            lw[idx] = W1[(kc + (idx >> 6)) * 64 + (idx & 63)];
        }
#pragma unroll
        for (int r = 0; r < 16; ++r) {
            int m = (tid >> 6) + r * 4;
            int node = node0 + m;
            float v = (node < n) ? x[node * FIN + kc + kl] : 0.f;
            lx[kl * 68 + m] = v;
        }
        __syncthreads();

#pragma unroll 8
        for (int k = 0; k < 64; ++k) {
            const float4 av = *reinterpret_cast<const float4*>(&lx[k * 68 + ty * 4]);
            const float4 bv = *reinterpret_cast<const float4*>(&lw[k * 64 + tx * 4]);
            float a[4] = {av.x, av.y, av.z, av.w};
            float b[4] = {bv.x, bv.y, bv.z, bv.w};
#pragma unroll
            for (int i = 0; i < 4; ++i)
#pragma unroll
                for (int j = 0; j < 4; ++j)
                    acc[i][j] = fmaf(a[i], b[j], acc[i][j]);
        }
    }

#pragma unroll
    for (int i = 0; i < 4; ++i) {
        int node = node0 + ty * 4 + i;
        if (node < n) {
            float4 o = make_float4(acc[i][0], acc[i][1], acc[i][2], acc[i][3]);
            *reinterpret_cast<float4*>(&h1[node * 64 + tx * 4]) = o;
        }
    }
}

// ---------------- fused agg1 + self-loop + bias + relu ----------------
// one wave per node; lane = feature (64)
__global__ __launch_bounds__(256) void agg1_kernel(
    const int* __restrict__ offs, const int* __restrict__ deg,
    const int* __restrict__ sRow, const float* __restrict__ sNorm,
    const float* __restrict__ h1, const float* __restrict__ dinv,
    const float* __restrict__ b1, float* __restrict__ h, int n) {
    int tid = threadIdx.x;
    int lane = tid & 63;
    int node = blockIdx.x * 4 + (tid >> 6);
    if (node >= n) return;
    int start = offs[node];
    int cnt = deg[node];
    float acc = 0.f;
    int k = 0;
    for (; k + 1 < cnt; k += 2) {
        int r0 = sRow[start + k], r1 = sRow[start + k + 1];
        float n0 = sNorm[start + k], n1 = sNorm[start + k + 1];
        float v0 = h1[(size_t)r0 * 64 + lane];
        float v1 = h1[(size_t)r1 * 64 + lane];
        acc = fmaf(v0, n0, acc);
        acc = fmaf(v1, n1, acc);
    }
    if (k < cnt) {
        int r0 = sRow[start + k];
        float n0 = sNorm[start + k];
        acc = fmaf(h1[(size_t)r0 * 64 + lane], n0, acc);
    }
    float di = dinv[node];
    float v = fmaf(h1[(size_t)node * 64 + lane], di * di, acc) + b1[lane];
    h[(size_t)node * 64 + lane] = fmaxf(v, 0.f);
}

// ---------------- GEMM2: h2[N,40] = h[N,64] @ W2[64,40] ----------------
__global__ __launch_bounds__(256) void gemm2_kernel(const float* __restrict__ h,
                                                    const float* __restrict__ W2,
                                                    float* __restrict__ h2, int n) {
    __shared__ float lw[64 * 40];
    int tid = threadIdx.x;
#pragma unroll
    for (int r = 0; r < 10; ++r) lw[tid + r * 256] = W2[tid + r * 256];
    __syncthreads();
    int gid = blockIdx.x * 256 + tid;
    if (gid < n * FOUT) {
        int i = gid / FOUT;
        int j = gid - i * FOUT;
        const float* hrow = h + (size_t)i * 64;
        float acc = 0.f;
#pragma unroll
        for (int k = 0; k < 64; ++k) acc = fmaf(hrow[k], lw[k * FOUT + j], acc);
        h2[gid] = acc;
    }
}

// ---------------- fused agg2 + self-loop + bias + log_softmax ----------------
// one wave per node; lanes 0..39 = features
__global__ __launch_bounds__(256) void agg2_kernel(
    const int* __restrict__ offs, const int* __restrict__ deg,
    const int* __restrict__ sRow, const float* __restrict__ sNorm,
    const float* __restrict__ h2, const float* __restrict__ dinv,
    const float* __restrict__ b2, float* __restrict__ out, int n) {
    int tid = threadIdx.x;
    int lane = tid & 63;
    int node = blockIdx.x * 4 + (tid >> 6);
    if (node >= n) return;
    bool act = lane < FOUT;
    int start = offs[node];
    int cnt = deg[node];
    float acc = 0.f;
    int k = 0;
    for (; k + 1 < cnt; k += 2) {
        int r0 = sRow[start + k], r1 = sRow[start + k + 1];
        float n0 = sNorm[start + k], n1 = sNorm[start + k + 1];
        float v0 = act ? h2[(size_t)r0 * FOUT + lane] : 0.f;
        float v1 = act ? h2[(size_t)r1 * FOUT + lane] : 0.f;
        acc = fmaf(v0, n0, acc);
        acc = fmaf(v1, n1, acc);
    }
    if (k < cnt) {
        int r0 = sRow[start + k];
        float n0 = sNorm[start + k];
        float v0 = act ? h2[(size_t)r0 * FOUT + lane] : 0.f;
        acc = fmaf(v0, n0, acc);
    }
    float di = dinv[node];
    float dd = di * di;
    float raw = 0.f, v = -INFINITY;
    if (act) {
        raw = acc + h2[(size_t)node * FOUT + lane] * dd + b2[lane];
        v = raw;
    }
    float m = v;
#pragma unroll
    for (int off = 32; off > 0; off >>= 1) m = fmaxf(m, __shfl_down(m, off));
    m = __shfl(m, 0);
    float ex = act ? expf(raw - m) : 0.f;
    float s = ex;
#pragma unroll
    for (int off = 32; off > 0; off >>= 1) s += __shfl_down(s, off);
    s = __shfl(s, 0);
    float ls = logf(s);
    if (act) out[(size_t)node * FOUT + lane] = raw - m - ls;
}

// ---------------------------------------------------------------------------
extern "C" void kernel_launch(void* const* d_in, const int* in_sizes, int n_in,
                              void* d_out, int out_size, void* d_ws, size_t ws_size,
                              hipStream_t stream) {
    const float* x  = (const float*)d_in[0];
    const int*   ei = (const int*)d_in[1];
    const float* W1 = (const float*)d_in[2];
    const float* b1 = (const float*)d_in[3];
    const float* W2 = (const float*)d_in[4];
    const float* b2 = (const float*)d_in[5];
    float* out = (float*)d_out;

    int n = in_sizes[0] / FIN;        // 100000
    int E = in_sizes[1] / 2;          // 1600000
    const int* row = ei;
    const int* col = ei + E;

    // workspace layout (4-byte words), total ~65.6 MB
    int* wsi = (int*)d_ws;
    const size_t NR = 100352;                 // n rounded to 512
    int*   deg    = wsi;                      // [n]
    float* dinv   = (float*)(wsi + NR);       // [n]
    int*   offs   = wsi + 2 * NR;             // [n]
    int*   cursor = wsi + 3 * NR;             // [n]
    int*   bsums  = wsi + 4 * NR;             // [512]
    int*   sRow   = wsi + 4 * NR + 512;       // [E]
    float* sNorm  = (float*)(sRow + (size_t)E);        // [E]
    float* h1     = sNorm + (size_t)E;                 // [n*64]
    float* h      = h1 + (size_t)n * 64;               // [n*64]
    float* h2     = h1;  // alias: h1 dead after agg1_kernel; h2 is [n*40]

    int nb = (n + 255) / 256;   // 391

    // ---- CSR build ----
    hipMemsetAsync(deg, 0, (size_t)n * 4, stream);
    hist_kernel<<<(E + 255) / 256, 256, 0, stream>>>(col, deg, E);
    dinv_kernel<<<nb, 256, 0, stream>>>(deg, dinv, n);
    scan1_kernel<<<nb, 256, 0, stream>>>(deg, offs, bsums, n);
    scan2_kernel<<<1, 512, 0, stream>>>(bsums, nb);
    scan3_kernel<<<nb, 256, 0, stream>>>(offs, bsums, cursor, n);
    build_kernel<<<(E + 255) / 256, 256, 0, stream>>>(row, col, dinv, cursor, sRow, sNorm, E);

    // ---- layer 1 ----
    gemm1_kernel<<<(n + 63) / 64, 256, 0, stream>>>(x, W1, h1, n);
    agg1_kernel<<<(n + 3) / 4, 256, 0, stream>>>(offs, deg, sRow, sNorm, h1, dinv, b1, h, n);
    // h1 dead; h holds post-relu features

    // ---- layer 2 ----
    gemm2_kernel<<<(n * FOUT + 255) / 256, 256, 0, stream>>>(h, W2, h2, n);
    agg2_kernel<<<(n + 3) / 4, 256, 0, stream>>>(offs, deg, sRow, sNorm, h2, dinv, b2, out, n);
}

// Round 3
// 680.499 us; speedup vs baseline: 1.7864x; 1.2366x over previous
//
#include <hip/hip_runtime.h>
#include <math.h>

// ---------------------------------------------------------------------------
// GCN 2-layer: h1 = relu(gcnconv(x,W1,b1)); out = log_softmax(gcnconv(h1,W2,b2))
// R2: gemm1 via bf16 MFMA (fp32->bf16 convert in staging), h1 stored bf16,
// CSR-by-destination gather aggregation (no atomics in hot path).
// N=100000, E=1600000, F: 512 -> 64 -> 40
// ---------------------------------------------------------------------------

#define FIN 512
#define FHID 64
#define FOUT 40

typedef __attribute__((ext_vector_type(8))) short short8;
typedef __attribute__((ext_vector_type(4))) float f32x4;
typedef unsigned short ushort_t;
typedef unsigned int uint_t;

__device__ __forceinline__ ushort_t bf16_rn(float f) {
    union { float f; uint_t u; } v; v.f = f;
    uint_t r = v.u + 0x7FFF + ((v.u >> 16) & 1);
    return (ushort_t)(r >> 16);
}
__device__ __forceinline__ uint_t pack_bf16(float a, float b) {
    return (uint_t)bf16_rn(a) | ((uint_t)bf16_rn(b) << 16);
}
__device__ __forceinline__ float bf16_to_f(ushort_t u) {
    union { uint_t i; float f; } t; t.i = ((uint_t)u) << 16; return t.f;
}

// ---------------- histogram of in-degree (int) ----------------
__global__ void hist_kernel(const int* __restrict__ col, int* __restrict__ deg, int E) {
    int e = blockIdx.x * 256 + threadIdx.x;
    if (e < E) atomicAdd(&deg[col[e]], 1);
}

__global__ void dinv_kernel(const int* __restrict__ deg, float* __restrict__ dinv, int n) {
    int i = blockIdx.x * 256 + threadIdx.x;
    if (i < n) dinv[i] = rsqrtf((float)deg[i] + 1.0f);
}

// ---------------- scan ----------------
__global__ void scan1_kernel(const int* __restrict__ deg, int* __restrict__ offs,
                             int* __restrict__ bsums, int n) {
    __shared__ int tmp[256];
    int tid = threadIdx.x;
    int i = blockIdx.x * 256 + tid;
    int v = (i < n) ? deg[i] : 0;
    tmp[tid] = v;
    __syncthreads();
    for (int off = 1; off < 256; off <<= 1) {
        int t = (tid >= off) ? tmp[tid - off] : 0;
        __syncthreads();
        tmp[tid] += t;
        __syncthreads();
    }
    if (i < n) offs[i] = tmp[tid] - v;
    if (tid == 255) bsums[blockIdx.x] = tmp[255];
}

__global__ void scan2_kernel(int* __restrict__ bsums, int nb) {
    __shared__ int tmp[512];
    int tid = threadIdx.x;
    int v = (tid < nb) ? bsums[tid] : 0;
    tmp[tid] = v;
    __syncthreads();
    for (int off = 1; off < 512; off <<= 1) {
        int t = (tid >= off) ? tmp[tid - off] : 0;
        __syncthreads();
        tmp[tid] += t;
        __syncthreads();
    }
    if (tid < nb) bsums[tid] = tmp[tid] - v;
}

__global__ void scan3_kernel(int* __restrict__ offs, const int* __restrict__ bsums,
                             int* __restrict__ cursor, int n) {
    int i = blockIdx.x * 256 + threadIdx.x;
    if (i < n) {
        int o = offs[i] + bsums[blockIdx.x];
        offs[i] = o;
        cursor[i] = o;
    }
}

// ---------------- build dest-sorted edge list ----------------
__global__ void build_kernel(const int* __restrict__ row, const int* __restrict__ col,
                             const float* __restrict__ dinv, int* __restrict__ cursor,
                             int* __restrict__ sRow, float* __restrict__ sNorm, int E) {
    int e = blockIdx.x * 256 + threadIdx.x;
    if (e < E) {
        int r = row[e], c = col[e];
        float nm = dinv[r] * dinv[c];
        int pos = atomicAdd(&cursor[c], 1);
        sRow[pos] = r;
        sNorm[pos] = nm;
    }
}

// ---------------- W1 transpose + bf16: Wt[n][k] = bf16(W1[k][n]) ----------------
__global__ void w1t_kernel(const float* __restrict__ W1, ushort_t* __restrict__ Wt) {
    int idx = blockIdx.x * 256 + threadIdx.x;   // 32768
    int nrow = idx >> 9;        // 0..63
    int k = idx & 511;
    Wt[idx] = bf16_rn(W1[k * 64 + nrow]);
}

// ---------------- GEMM1 (MFMA): h1b[N,64] = bf16( x[N,512] @ W1[512,64] ) ----
// block = 256 thr (4 waves); BM=128, BN=64, BK=64; wave w -> rows [32w,32w+32)
#define LDA 72
#define LDB 72
__global__ __launch_bounds__(256) void gemm1_kernel(
    const float* __restrict__ x, const ushort_t* __restrict__ Wt,
    ushort_t* __restrict__ h1b, int n) {
    __shared__ ushort_t lA[128 * LDA];   // 18432 B  [row][k]
    __shared__ ushort_t lB[64 * LDB];    //  9216 B  [n][k]

    int tid = threadIdx.x;
    int wave = tid >> 6, lane = tid & 63;
    int quad = lane >> 4, m16 = lane & 15;
    int node0 = blockIdx.x * 128;

    f32x4 zero = {0.f, 0.f, 0.f, 0.f};
    f32x4 acc[2][4];
#pragma unroll
    for (int mt = 0; mt < 2; ++mt)
#pragma unroll
        for (int nt = 0; nt < 4; ++nt) acc[mt][nt] = zero;

    for (int kc = 0; kc < FIN; kc += 64) {
        __syncthreads();
        // stage A: 128x64 fp32 -> bf16
#pragma unroll
        for (int i = 0; i < 8; ++i) {
            int p = tid + i * 256;        // 0..2047 float4 slots, 16 per row
            int r = p >> 4;
            int k4 = p & 15;
            int node = node0 + r;
            float4 v = make_float4(0.f, 0.f, 0.f, 0.f);
            if (node < n) v = *reinterpret_cast<const float4*>(&x[(size_t)node * FIN + kc + k4 * 4]);
            uint2 u = make_uint2(pack_bf16(v.x, v.y), pack_bf16(v.z, v.w));
            *reinterpret_cast<uint2*>(&lA[r * LDA + k4 * 4]) = u;
        }
        // stage B: 64x64 bf16 (already n-major in Wt)
#pragma unroll
        for (int i = 0; i < 2; ++i) {
            int p = tid + i * 256;        // 0..511, 8 16B-segs per row
            int nr = p >> 3;
            int seg = p & 7;
            uint4 v = *reinterpret_cast<const uint4*>(&Wt[(size_t)nr * FIN + kc + seg * 8]);
            *reinterpret_cast<uint4*>(&lB[nr * LDB + seg * 8]) = v;
        }
        __syncthreads();
        // compute: 2 k-steps of 32
#pragma unroll
        for (int kk = 0; kk < 2; ++kk) {
            short8 a[2], b[4];
#pragma unroll
            for (int mt = 0; mt < 2; ++mt)
                a[mt] = *reinterpret_cast<const short8*>(
                    &lA[(wave * 32 + mt * 16 + m16) * LDA + kk * 32 + quad * 8]);
#pragma unroll
            for (int nt = 0; nt < 4; ++nt)
                b[nt] = *reinterpret_cast<const short8*>(
                    &lB[(nt * 16 + m16) * LDB + kk * 32 + quad * 8]);
#pragma unroll
            for (int mt = 0; mt < 2; ++mt)
#pragma unroll
                for (int nt = 0; nt < 4; ++nt)
                    acc[mt][nt] = __builtin_amdgcn_mfma_f32_16x16x32_bf16(
                        a[mt], b[nt], acc[mt][nt], 0, 0, 0);
        }
    }

    // epilogue: C/D layout col=lane&15, row=quad*4+reg
#pragma unroll
    for (int mt = 0; mt < 2; ++mt) {
#pragma unroll
        for (int reg = 0; reg < 4; ++reg) {
            int node = node0 + wave * 32 + mt * 16 + quad * 4 + reg;
            if (node < n) {
#pragma unroll
                for (int nt = 0; nt < 4; ++nt)
                    h1b[(size_t)node * 64 + nt * 16 + m16] = bf16_rn(acc[mt][nt][reg]);
            }
        }
    }
}

// ---------------- fused agg1 + self-loop + bias + relu (h1 in bf16) ----------
__global__ __launch_bounds__(256) void agg1_kernel(
    const int* __restrict__ offs, const int* __restrict__ deg,
    const int* __restrict__ sRow, const float* __restrict__ sNorm,
    const ushort_t* __restrict__ h1b, const float* __restrict__ dinv,
    const float* __restrict__ b1, float* __restrict__ h, int n) {
    int tid = threadIdx.x;
    int lane = tid & 63;
    int node = blockIdx.x * 4 + (tid >> 6);
    if (node >= n) return;
    int start = offs[node];
    int cnt = deg[node];
    float acc0 = 0.f, acc1 = 0.f;
    int k = 0;
    for (; k + 3 < cnt; k += 4) {
        int r0 = sRow[start + k], r1 = sRow[start + k + 1];
        int r2 = sRow[start + k + 2], r3 = sRow[start + k + 3];
        float n0 = sNorm[start + k], n1 = sNorm[start + k + 1];
        float n2 = sNorm[start + k + 2], n3 = sNorm[start + k + 3];
        float v0 = bf16_to_f(h1b[(size_t)r0 * 64 + lane]);
        float v1 = bf16_to_f(h1b[(size_t)r1 * 64 + lane]);
        float v2 = bf16_to_f(h1b[(size_t)r2 * 64 + lane]);
        float v3 = bf16_to_f(h1b[(size_t)r3 * 64 + lane]);
        acc0 = fmaf(v0, n0, acc0);
        acc1 = fmaf(v1, n1, acc1);
        acc0 = fmaf(v2, n2, acc0);
        acc1 = fmaf(v3, n3, acc1);
    }
    for (; k < cnt; ++k) {
        int r0 = sRow[start + k];
        float n0 = sNorm[start + k];
        acc0 = fmaf(bf16_to_f(h1b[(size_t)r0 * 64 + lane]), n0, acc0);
    }
    float acc = acc0 + acc1;
    float di = dinv[node];
    float v = fmaf(bf16_to_f(h1b[(size_t)node * 64 + lane]), di * di, acc) + b1[lane];
    h[(size_t)node * 64 + lane] = fmaxf(v, 0.f);
}

// ---------------- GEMM2: h2[N,40] = h[N,64] @ W2[64,40] ----------------
__global__ __launch_bounds__(256) void gemm2_kernel(const float* __restrict__ h,
                                                    const float* __restrict__ W2,
                                                    float* __restrict__ h2, int n) {
    __shared__ float lw[64 * 40];
    int tid = threadIdx.x;
#pragma unroll
    for (int r = 0; r < 10; ++r) lw[tid + r * 256] = W2[tid + r * 256];
    __syncthreads();
    int gid = blockIdx.x * 256 + tid;
    if (gid < n * FOUT) {
        int i = gid / FOUT;
        int j = gid - i * FOUT;
        const float* hrow = h + (size_t)i * 64;
        float acc = 0.f;
#pragma unroll
        for (int k = 0; k < 64; ++k) acc = fmaf(hrow[k], lw[k * FOUT + j], acc);
        h2[gid] = acc;
    }
}

// ---------------- fused agg2 + self-loop + bias + log_softmax ----------------
__global__ __launch_bounds__(256) void agg2_kernel(
    const int* __restrict__ offs, const int* __restrict__ deg,
    const int* __restrict__ sRow, const float* __restrict__ sNorm,
    const float* __restrict__ h2, const float* __restrict__ dinv,
    const float* __restrict__ b2, float* __restrict__ out, int n) {
    int tid = threadIdx.x;
    int lane = tid & 63;
    int node = blockIdx.x * 4 + (tid >> 6);
    if (node >= n) return;
    bool act = lane < FOUT;
    int start = offs[node];
    int cnt = deg[node];
    float acc0 = 0.f, acc1 = 0.f;
    int k = 0;
    for (; k + 3 < cnt; k += 4) {
        int r0 = sRow[start + k], r1 = sRow[start + k + 1];
        int r2 = sRow[start + k + 2], r3 = sRow[start + k + 3];
        float n0 = sNorm[start + k], n1 = sNorm[start + k + 1];
        float n2 = sNorm[start + k + 2], n3 = sNorm[start + k + 3];
        float v0 = act ? h2[(size_t)r0 * FOUT + lane] : 0.f;
        float v1 = act ? h2[(size_t)r1 * FOUT + lane] : 0.f;
        float v2 = act ? h2[(size_t)r2 * FOUT + lane] : 0.f;
        float v3 = act ? h2[(size_t)r3 * FOUT + lane] : 0.f;
        acc0 = fmaf(v0, n0, acc0);
        acc1 = fmaf(v1, n1, acc1);
        acc0 = fmaf(v2, n2, acc0);
        acc1 = fmaf(v3, n3, acc1);
    }
    for (; k < cnt; ++k) {
        int r0 = sRow[start + k];
        float n0 = sNorm[start + k];
        float v0 = act ? h2[(size_t)r0 * FOUT + lane] : 0.f;
        acc0 = fmaf(v0, n0, acc0);
    }
    float acc = acc0 + acc1;
    float di = dinv[node];
    float dd = di * di;
    float raw = 0.f, v = -INFINITY;
    if (act) {
        raw = acc + h2[(size_t)node * FOUT + lane] * dd + b2[lane];
        v = raw;
    }
    float m = v;
#pragma unroll
    for (int off = 32; off > 0; off >>= 1) m = fmaxf(m, __shfl_down(m, off));
    m = __shfl(m, 0);
    float ex = act ? expf(raw - m) : 0.f;
    float s = ex;
#pragma unroll
    for (int off = 32; off > 0; off >>= 1) s += __shfl_down(s, off);
    s = __shfl(s, 0);
    float ls = logf(s);
    if (act) out[(size_t)node * FOUT + lane] = raw - m - ls;
}

// ---------------------------------------------------------------------------
extern "C" void kernel_launch(void* const* d_in, const int* in_sizes, int n_in,
                              void* d_out, int out_size, void* d_ws, size_t ws_size,
                              hipStream_t stream) {
    const float* x  = (const float*)d_in[0];
    const int*   ei = (const int*)d_in[1];
    const float* W1 = (const float*)d_in[2];
    const float* b1 = (const float*)d_in[3];
    const float* W2 = (const float*)d_in[4];
    const float* b2 = (const float*)d_in[5];
    float* out = (float*)d_out;

    int n = in_sizes[0] / FIN;        // 100000
    int E = in_sizes[1] / 2;          // 1600000
    const int* row = ei;
    const int* col = ei + E;

    // workspace layout (4-byte words), ~68.9 MB total
    int* wsi = (int*)d_ws;
    const size_t NR = 100352;                       // n rounded up
    int*      deg    = wsi;                         // [NR]
    float*    dinv   = (float*)(wsi + NR);          // [NR]
    int*      offs   = wsi + 2 * NR;                // [NR]
    int*      cursor = wsi + 3 * NR;                // [NR]
    int*      bsums  = wsi + 4 * NR;                // [512]
    ushort_t* Wt     = (ushort_t*)(wsi + 4 * NR + 512);      // [64*512] bf16
    int*      sRow   = wsi + 4 * NR + 512 + 16384;           // [E]
    float*    sNorm  = (float*)(sRow + (size_t)E);           // [E]
    ushort_t* h1b    = (ushort_t*)(sNorm + (size_t)E);       // [n*64] bf16
    float*    h      = (float*)(h1b + (size_t)n * 64);       // [n*64]
    float*    h2     = h + (size_t)n * 64;                   // [n*40]

    int nb = (n + 255) / 256;   // 391

    // ---- CSR build ----
    hipMemsetAsync(deg, 0, (size_t)n * 4, stream);
    hist_kernel<<<(E + 255) / 256, 256, 0, stream>>>(col, deg, E);
    dinv_kernel<<<nb, 256, 0, stream>>>(deg, dinv, n);
    scan1_kernel<<<nb, 256, 0, stream>>>(deg, offs, bsums, n);
    scan2_kernel<<<1, 512, 0, stream>>>(bsums, nb);
    scan3_kernel<<<nb, 256, 0, stream>>>(offs, bsums, cursor, n);
    build_kernel<<<(E + 255) / 256, 256, 0, stream>>>(row, col, dinv, cursor, sRow, sNorm, E);

    // ---- layer 1 ----
    w1t_kernel<<<128, 256, 0, stream>>>(W1, Wt);
    gemm1_kernel<<<(n + 127) / 128, 256, 0, stream>>>(x, Wt, h1b, n);
    agg1_kernel<<<(n + 3) / 4, 256, 0, stream>>>(offs, deg, sRow, sNorm, h1b, dinv, b1, h, n);

    // ---- layer 2 ----
    gemm2_kernel<<<(n * FOUT + 255) / 256, 256, 0, stream>>>(h, W2, h2, n);
    agg2_kernel<<<(n + 3) / 4, 256, 0, stream>>>(offs, deg, sRow, sNorm, h2, dinv, b2, out, n);
}